// Round 11
// baseline (329.170 us; speedup 1.0000x reference)
//
#include <hip/hip_runtime.h>
#include <hip/hip_bf16.h>

// Problem constants (B=2, S=2048, D=2048, NH=32, NKV=8, HD=64, NREP=4)
#define S_LEN 2048
#define DMODEL 2048
#define N_H 32
#define N_KV 8
#define H_D 64
#define ROWS 4096   // B*S
#define QKV_LD 3072 // fused qkv row stride: q[0:2048) k[2048:2560) v[2560:3072)

typedef __bf16 bf16x8 __attribute__((ext_vector_type(8)));
typedef float f32x4 __attribute__((ext_vector_type(4)));

// fp32 -> bf16 raw bits, round-to-nearest-even
static __device__ __forceinline__ unsigned short f2bf(float f) {
  unsigned int u = __float_as_uint(f);
  u += 0x7FFFu + ((u >> 16) & 1u);
  return (unsigned short)(u >> 16);
}
// fp32 -> bf16 truncation (1 op; P and l use the same truncated values so
// the truncation bias cancels in P·V / l)
static __device__ __forceinline__ unsigned short f2bf_tr(float f) {
  return (unsigned short)(__float_as_uint(f) >> 16);
}
static __device__ __forceinline__ float bf2f(unsigned short s) {
  return __uint_as_float((unsigned int)s << 16);
}

// async global->LDS, 16 B per lane. LDS dest = wave-uniform base + lane*16.
static __device__ __forceinline__ void async16(const void* g, void* l) {
  __builtin_amdgcn_global_load_lds(
      (const __attribute__((address_space(1))) unsigned int*)g,
      (__attribute__((address_space(3))) unsigned int*)l, 16, 0, 0);
}

// ---------------------------------------------------------------------------
// fp32 -> bf16 bulk convert (8 elems/thread) — fallback path only
// ---------------------------------------------------------------------------
__global__ __launch_bounds__(256) void cvt_bf16_k(
    const float* __restrict__ in, unsigned short* __restrict__ out) {
  const size_t i = ((size_t)blockIdx.x * 256 + threadIdx.x) * 8;
  const float4 a = *(const float4*)&in[i];
  const float4 b = *(const float4*)&in[i + 4];
  union { unsigned short u[8]; uint4 v; } p;
  p.u[0] = f2bf(a.x); p.u[1] = f2bf(a.y); p.u[2] = f2bf(a.z); p.u[3] = f2bf(a.w);
  p.u[4] = f2bf(b.x); p.u[5] = f2bf(b.y); p.u[6] = f2bf(b.z); p.u[7] = f2bf(b.w);
  *(uint4*)&out[i] = p.v;
}

// ---------------------------------------------------------------------------
// Combined prep: z=0..3 transpose fp32 weights -> bf16 wqkvT/woT blocks;
// z=4: straight cvt x fp32 -> xb bf16.
// ---------------------------------------------------------------------------
__global__ __launch_bounds__(256) void prep_all_k(
    const float* __restrict__ x, const float* __restrict__ wq,
    const float* __restrict__ wk, const float* __restrict__ wv,
    const float* __restrict__ wo, unsigned short* __restrict__ xb,
    unsigned short* __restrict__ wqkvT, unsigned short* __restrict__ woT) {
  const int z = blockIdx.z;
  if (z == 4) {
    const size_t i =
        (((size_t)blockIdx.y * 64 + blockIdx.x) * 256 + threadIdx.x) * 8;
    const float4 a = *(const float4*)&x[i];
    const float4 b = *(const float4*)&x[i + 4];
    union { unsigned short u[8]; uint4 v; } p;
    p.u[0] = f2bf(a.x); p.u[1] = f2bf(a.y); p.u[2] = f2bf(a.z); p.u[3] = f2bf(a.w);
    p.u[4] = f2bf(b.x); p.u[5] = f2bf(b.y); p.u[6] = f2bf(b.z); p.u[7] = f2bf(b.w);
    *(uint4*)&xb[i] = p.v;
    return;
  }
  const float* in;
  unsigned short* out;
  int C;
  if (z == 0)      { in = wq; out = wqkvT;                  C = 2048; }
  else if (z == 1) { in = wk; out = wqkvT + 2048ull * 2048; C = 512;  }
  else if (z == 2) { in = wv; out = wqkvT + 2560ull * 2048; C = 512;  }
  else             { in = wo; out = woT;                    C = 2048; }
  if (blockIdx.x * 32 >= C) return;

  __shared__ unsigned short tile[32][33];
  const int tx = threadIdx.x & 31;
  const int ty = threadIdx.x >> 5;
  const int r0 = blockIdx.y * 32;  // K rows of input
  const int c0 = blockIdx.x * 32;  // C cols of input
#pragma unroll
  for (int i = 0; i < 32; i += 8)
    tile[ty + i][tx] = f2bf(in[(size_t)(r0 + ty + i) * C + c0 + tx]);
  __syncthreads();
#pragma unroll
  for (int i = 0; i < 32; i += 8)
    out[(size_t)(c0 + ty + i) * 2048 + r0 + tx] = tile[tx][ty + i];
}

// log2(e) / sqrt(HD): softmax base-2 conversion + 1/sqrt(d), folded into q
#define SCALE_LOG2E 0.18033688011112042f

// ---------------------------------------------------------------------------
// Fused RoPE (blocks 0..20479) + v->vT transpose (blocks 20480..22527).
// q is PRE-SCALED by SCALE_LOG2E so QK^T comes out in base-2 exponent units.
// vT: qkv cols 2560..3071 ([4096][512] view, ld QKV_LD) -> vT [512][4096].
// ---------------------------------------------------------------------------
__global__ __launch_bounds__(256) void rope_vt_k(
    unsigned short* __restrict__ qkv, unsigned short* __restrict__ vT,
    const float* __restrict__ fc, const float* __restrict__ fs) {
  const int blk = blockIdx.x;
  if (blk < 20480) {
    const int PQ = ROWS * N_H * (H_D / 2);   // 4194304
    const int PK = ROWS * N_KV * (H_D / 2);  // 1048576
    const int idx = blk * 256 + threadIdx.x;
    if (idx >= PQ + PK) return;
    unsigned short* base;
    float c, sn;
    bool isq;
    if (idx < PQ) {
      const int i = idx & 31;
      const int h = (idx >> 5) & 31;
      const int row = idx >> 10;
      const int s = row & (S_LEN - 1);
      c = fc[s * 32 + i];
      sn = fs[s * 32 + i];
      base = qkv + (size_t)row * QKV_LD + h * H_D + 2 * i;
      isq = true;
    } else {
      const int p = idx - PQ;
      const int i = p & 31;
      const int h = (p >> 5) & 7;
      const int row = p >> 8;
      const int s = row & (S_LEN - 1);
      c = fc[s * 32 + i];
      sn = fs[s * 32 + i];
      base = qkv + (size_t)row * QKV_LD + 2048 + h * H_D + 2 * i;
      isq = false;
    }
    const float x0 = bf2f(base[0]);
    const float x1 = bf2f(base[1]);
    const float sc = isq ? SCALE_LOG2E : 1.0f;
    base[0] = f2bf((x0 * c - x1 * sn) * sc);
    base[1] = f2bf((x0 * sn + x1 * c) * sc);
  } else {
    __shared__ unsigned short tile[32][33];
    const int t = blk - 20480;        // 0..2047
    const int bx = t & 15;            // C/32 = 16
    const int by = t >> 4;            // R/32 = 128
    const unsigned short* in = qkv + 2560;
    const int tx = threadIdx.x & 31;
    const int ty = threadIdx.x >> 5;
    const int r0 = by * 32;
    const int c0 = bx * 32;
#pragma unroll
    for (int i = 0; i < 32; i += 8)
      tile[ty + i][tx] = in[(size_t)(r0 + ty + i) * QKV_LD + c0 + tx];
    __syncthreads();
#pragma unroll
    for (int i = 0; i < 32; i += 8)
      vT[(size_t)(c0 + ty + i) * ROWS + r0 + tx] = tile[tx][ty + i];
  }
}

// ---------------------------------------------------------------------------
// m97-style MFMA GEMM, BK=64: two verified BK-32 sub-stages (As[2]/Bs[2],
// per-half layout identical to m97) per barrier pair -> half the barrier
// drains. C[M][N] = A[M][K] @ BT[N][K]^T, both bf16, 128x128 tile.
// ---------------------------------------------------------------------------
template <int STORE_BF16>
__global__ __launch_bounds__(256) void gemm_bt_k(
    const unsigned short* __restrict__ A, const unsigned short* __restrict__ BT,
    void* __restrict__ Cp, int M, int N, int K, int lda) {
  __shared__ __align__(16) unsigned short As[2][128 * 32];
  __shared__ __align__(16) unsigned short Bs[2][128 * 32];
  const int tid = threadIdx.x;
  const int wave = tid >> 6;
  const int lane = tid & 63;
  const int quad = lane >> 4;
  const int l16 = lane & 15;
  const int m0 = blockIdx.x * 128;
  const int n0 = blockIdx.y * 128;
  const int wm = (wave >> 1) * 64;
  const int wn = (wave & 1) * 64;
  const int rsub = lane >> 2;       // 0..15
  const int coff = (lane & 3) * 8;  // elem offset of 16B chunk
  f32x4 acc[4][4] = {};

  for (int kt = 0; kt < K; kt += 64) {
    __syncthreads();
#pragma unroll
    for (int hh = 0; hh < 2; hh++) {
#pragma unroll
      for (int t = 0; t < 2; t++) {
        const int row = wave * 32 + t * 16 + rsub;
        async16(&A[(size_t)(m0 + row) * lda + kt + hh * 32 + coff],
                &As[hh][(wave * 32 + t * 16) * 32]);
        async16(&BT[(size_t)(n0 + row) * K + kt + hh * 32 + coff],
                &Bs[hh][(wave * 32 + t * 16) * 32]);
      }
    }
    __syncthreads();
#pragma unroll
    for (int hh = 0; hh < 2; hh++) {
      bf16x8 af[4], bfr[4];
#pragma unroll
      for (int i = 0; i < 4; i++)
        af[i] = *(const bf16x8*)&As[hh][(wm + i * 16 + l16) * 32 + quad * 8];
#pragma unroll
      for (int j = 0; j < 4; j++)
        bfr[j] = *(const bf16x8*)&Bs[hh][(wn + j * 16 + l16) * 32 + quad * 8];
#pragma unroll
      for (int i = 0; i < 4; i++)
#pragma unroll
        for (int j = 0; j < 4; j++)
          acc[i][j] = __builtin_amdgcn_mfma_f32_16x16x32_bf16(af[i], bfr[j],
                                                              acc[i][j], 0, 0, 0);
    }
  }

  // Epilogue: C/D layout col = lane&15, row = quad*4 + reg  [m89/m91 verified]
#pragma unroll
  for (int i = 0; i < 4; i++) {
#pragma unroll
    for (int e = 0; e < 4; e++) {
      const int mrow = m0 + wm + i * 16 + quad * 4 + e;
#pragma unroll
      for (int j = 0; j < 4; j++) {
        const int ncol = n0 + wn + j * 16 + l16;
        const float val = acc[i][j][e];
        if (STORE_BF16) {
          ((unsigned short*)Cp)[(size_t)mrow * N + ncol] = f2bf(val);
        } else {
          ((float*)Cp)[(size_t)mrow * N + ncol] = val;
        }
      }
    }
  }
}

// ---------------------------------------------------------------------------
// Fallback MFMA GEMM (round-4): C[M][N] = A[M][K] @ B[K][N], B fp32 native.
// ---------------------------------------------------------------------------
template <int AF32, int STORE_BF16>
__global__ __launch_bounds__(256) void gemm_k(
    const void* __restrict__ Ap, const float* __restrict__ B,
    void* __restrict__ Cp, int M, int N, int K) {
  constexpr int LDP = 40;
  __shared__ __align__(16) unsigned short As[128 * LDP];
  __shared__ __align__(16) unsigned short Bs[128 * LDP];
  const int tid = threadIdx.x;
  const int wave = tid >> 6;
  const int lane = tid & 63;
  const int quad = lane >> 4;
  const int l16 = lane & 15;
  const int m0 = blockIdx.x * 128;
  const int n0 = blockIdx.y * 128;
  const int wm = (wave >> 1) * 64;
  const int wn = (wave & 1) * 64;
  f32x4 acc[4][4] = {};

  for (int kt = 0; kt < K; kt += 32) {
    __syncthreads();
    if (AF32) {
      const float* A = (const float*)Ap;
      for (int c = tid; c < 1024; c += 256) {
        const int r = c >> 3;
        const int cc = (c & 7) << 2;
        const float4 w = *(const float4*)&A[(size_t)(m0 + r) * K + kt + cc];
        union { unsigned short u[4]; uint2 v; } p;
        p.u[0] = f2bf(w.x); p.u[1] = f2bf(w.y);
        p.u[2] = f2bf(w.z); p.u[3] = f2bf(w.w);
        *(uint2*)&As[r * LDP + cc] = p.v;
      }
    } else {
      const unsigned short* A = (const unsigned short*)Ap;
      for (int c = tid; c < 512; c += 256) {
        const int r = c >> 2;
        const int cc = (c & 3) << 3;
        *(uint4*)&As[r * LDP + cc] =
            *(const uint4*)&A[(size_t)(m0 + r) * K + kt + cc];
      }
    }
    for (int c = tid; c < 1024; c += 256) {
      const int kr = c >> 5;
      const int nc = (c & 31) << 2;
      const float4 w = *(const float4*)&B[(size_t)(kt + kr) * N + n0 + nc];
      Bs[(nc + 0) * LDP + kr] = f2bf(w.x);
      Bs[(nc + 1) * LDP + kr] = f2bf(w.y);
      Bs[(nc + 2) * LDP + kr] = f2bf(w.z);
      Bs[(nc + 3) * LDP + kr] = f2bf(w.w);
    }
    __syncthreads();
    bf16x8 af[4], bfr[4];
#pragma unroll
    for (int i = 0; i < 4; i++)
      af[i] = *(const bf16x8*)&As[(wm + i * 16 + l16) * LDP + quad * 8];
#pragma unroll
    for (int j = 0; j < 4; j++)
      bfr[j] = *(const bf16x8*)&Bs[(wn + j * 16 + l16) * LDP + quad * 8];
#pragma unroll
    for (int i = 0; i < 4; i++)
#pragma unroll
      for (int j = 0; j < 4; j++)
        acc[i][j] =
            __builtin_amdgcn_mfma_f32_16x16x32_bf16(af[i], bfr[j], acc[i][j], 0, 0, 0);
  }
#pragma unroll
  for (int i = 0; i < 4; i++) {
#pragma unroll
    for (int e = 0; e < 4; e++) {
      const int mrow = m0 + wm + i * 16 + quad * 4 + e;
#pragma unroll
      for (int j = 0; j < 4; j++) {
        const int ncol = n0 + wn + j * 16 + l16;
        const float val = acc[i][j][e];
        if (STORE_BF16) {
          ((unsigned short*)Cp)[(size_t)mrow * N + ncol] = f2bf(val);
        } else {
          ((float*)Cp)[(size_t)mrow * N + ncol] = val;
        }
      }
    }
  }
}

// ---------------------------------------------------------------------------
// Fallback RoPE (separate q/k buffers)
// ---------------------------------------------------------------------------
__global__ __launch_bounds__(256) void rope_k(
    unsigned short* __restrict__ q, unsigned short* __restrict__ kk,
    const float* __restrict__ fc, const float* __restrict__ fs,
    int qstride, int kstride) {
  const int PQ = ROWS * N_H * (H_D / 2);
  const int PK = ROWS * N_KV * (H_D / 2);
  const int idx = blockIdx.x * 256 + threadIdx.x;
  if (idx >= PQ + PK) return;
  unsigned short* base;
  float c, sn;
  if (idx < PQ) {
    const int i = idx & 31;
    const int h = (idx >> 5) & 31;
    const int row = idx >> 10;
    const int s = row & (S_LEN - 1);
    c = fc[s * 32 + i];
    sn = fs[s * 32 + i];
    base = q + (size_t)row * qstride + h * H_D + 2 * i;
  } else {
    const int p = idx - PQ;
    const int i = p & 31;
    const int h = (p >> 5) & 7;
    const int row = p >> 8;
    const int s = row & (S_LEN - 1);
    c = fc[s * 32 + i];
    sn = fs[s * 32 + i];
    base = kk + (size_t)row * kstride + h * H_D + 2 * i;
  }
  const float x0 = bf2f(base[0]);
  const float x1 = bf2f(base[1]);
  base[0] = f2bf(x0 * c - x1 * sn);
  base[1] = f2bf(x0 * sn + x1 * c);
}

#define LK 72  // padded inner stride (elems); 144 B rows keep 16B alignment

// ---------------------------------------------------------------------------
// Pipelined balanced MFMA flash attention v7: NON-ONLINE softmax, 128 q-rows
// per block, V fragments read DIRECTLY from global vT (no Vt LDS buffer:
// 55->37 KB LDS, 2->4 blocks/CU). Per-lane V reads are 16B contiguous along
// the s-dim of vT (rows reused within the tile -> L1-resident). l row-sums
// via MFMA vs ones. grid (8, NH, B); block p handles q-blocks {p, 15-p}.
// ---------------------------------------------------------------------------
__global__ __launch_bounds__(256) void attn_mfma7_k(
    const unsigned short* __restrict__ qkv, const unsigned short* __restrict__ vT,
    unsigned short* __restrict__ ao) {
  const int pair = blockIdx.x, h = blockIdx.y, b = blockIdx.z;
  const int hk = h >> 2;
  const int tid = threadIdx.x;
  const int wave = tid >> 6;
  const int l16 = tid & 15;
  const int quad = (tid & 63) >> 4;
  const int rr = tid >> 2;        // 0..63 (key row for Ks staging)
  const int dc = (tid & 3) * 16;  // 16-elem chunk

  __shared__ __align__(16) unsigned short Ks[2][64 * LK];  // [key][d]
  __shared__ __align__(16) unsigned short Ps[4][32 * LK];  // wave-private

  bf16x8 ones;
#pragma unroll
  for (int j = 0; j < 8; j++) ones[j] = (__bf16)1.0f;

  const size_t kbase =
      (size_t)(b * S_LEN) * QKV_LD + 2048 + hk * H_D + dc;  // k cols
  // V fragment base: vT[(hk*64 + n*16 + l16)][b*2048 + kb + c*32 + quad*8]
  const size_t vfbase = (size_t)(hk * H_D + l16) * ROWS + b * S_LEN + quad * 8;

  for (int sel = 0; sel < 2; ++sel) {
    const int qb = sel ? (15 - pair) : pair;  // q-block of 128 rows
    const int row0 = qb * 128;
    const int ktiles = 2 * qb + 2;

    // Q fragments: A[m=l16][k=quad*8+j], two 16-row strips per wave
    bf16x8 af[2][2];
#pragma unroll
    for (int r = 0; r < 2; r++) {
      const size_t qrow =
          (size_t)(b * S_LEN + row0 + wave * 32 + r * 16 + l16);
#pragma unroll
      for (int c = 0; c < 2; c++)
        af[r][c] =
            *(const bf16x8*)&qkv[qrow * QKV_LD + h * H_D + c * 32 + quad * 8];
    }

    f32x4 o_acc[2][4] = {};
    f32x4 l_acc[2] = {};

    // Prefetch K tile 0 into registers, then stage into LDS buffer 0.
    uint4 rk0, rk1;
    {
      const size_t kro = kbase + (size_t)rr * QKV_LD;
      rk0 = *(const uint4*)&qkv[kro];
      rk1 = *(const uint4*)&qkv[kro + 8];
    }
    __syncthreads();  // prior-sel readers of LDS done before overwrite
    *(uint4*)&Ks[0][rr * LK + dc] = rk0;
    *(uint4*)&Ks[0][rr * LK + dc + 8] = rk1;

    int cur = 0;
    for (int kt = 0; kt < ktiles; ++kt) {
      const int kb = kt * 64;
      // Prefetch next K tile while this tile computes.
      if (kt + 1 < ktiles) {
        const size_t kro = kbase + (size_t)((kt + 1) * 64 + rr) * QKV_LD;
        rk0 = *(const uint4*)&qkv[kro];
        rk1 = *(const uint4*)&qkv[kro + 8];
      }
      // V fragments for this tile straight from global (issued pre-barrier
      // so the load latency overlaps the S-MFMA phase).
      bf16x8 bv[4][2];
#pragma unroll
      for (int n = 0; n < 4; n++)
#pragma unroll
        for (int c = 0; c < 2; c++)
          bv[n][c] =
              *(const bf16x8*)&vT[vfbase + (size_t)(n * 16) * ROWS + kb + c * 32];
      __syncthreads();  // Ks[cur] fully staged by all waves

      // S strips: each bk read feeds both row-strips' MFMAs.
      f32x4 sacc[2][4];
#pragma unroll
      for (int n = 0; n < 4; n++) {
        f32x4 z0 = {}, z1 = {};
#pragma unroll
        for (int c = 0; c < 2; c++) {
          const bf16x8 bk =
              *(const bf16x8*)&Ks[cur][(n * 16 + l16) * LK + c * 32 + quad * 8];
          z0 = __builtin_amdgcn_mfma_f32_16x16x32_bf16(af[0][c], bk, z0, 0, 0, 0);
          z1 = __builtin_amdgcn_mfma_f32_16x16x32_bf16(af[1][c], bk, z1, 0, 0, 0);
        }
        sacc[0][n] = z0;
        sacc[1][n] = z1;
      }

      // pe = exp2(s) (q pre-scaled); truncate to bf16; masked -> 0.
      const bool maybe_mask = (kt >= 2 * qb);
      const int krel0 = (kt - 2 * qb) * 64;  // valid only when maybe_mask
#pragma unroll
      for (int r = 0; r < 2; r++) {
        const int qrel = wave * 32 + r * 16 + quad * 4;  // + e
        if (maybe_mask) {
#pragma unroll
          for (int n = 0; n < 4; n++)
#pragma unroll
            for (int e = 0; e < 4; e++) {
              float pe = exp2f(sacc[r][n][e]);
              if ((krel0 + n * 16 + l16) > (qrel + e)) pe = 0.f;
              Ps[wave][(r * 16 + quad * 4 + e) * LK + n * 16 + l16] =
                  f2bf_tr(pe);
            }
        } else {
#pragma unroll
          for (int n = 0; n < 4; n++)
#pragma unroll
            for (int e = 0; e < 4; e++)
              Ps[wave][(r * 16 + quad * 4 + e) * LK + n * 16 + l16] =
                  f2bf_tr(exp2f(sacc[r][n][e]));
        }
      }
      // wave-private Ps: compiler inserts lgkmcnt wait; no barrier needed

      bf16x8 pf[2][2];
#pragma unroll
      for (int r = 0; r < 2; r++)
#pragma unroll
        for (int c = 0; c < 2; c++)
          pf[r][c] = *(const bf16x8*)&Ps[wave][(r * 16 + l16) * LK + c * 32 +
                                              quad * 8];
      // l row-sums via MFMA against ones.
#pragma unroll
      for (int c = 0; c < 2; c++) {
        l_acc[0] = __builtin_amdgcn_mfma_f32_16x16x32_bf16(pf[0][c], ones,
                                                           l_acc[0], 0, 0, 0);
        l_acc[1] = __builtin_amdgcn_mfma_f32_16x16x32_bf16(pf[1][c], ones,
                                                           l_acc[1], 0, 0, 0);
      }
#pragma unroll
      for (int n = 0; n < 4; n++)
#pragma unroll
        for (int c = 0; c < 2; c++) {
          o_acc[0][n] = __builtin_amdgcn_mfma_f32_16x16x32_bf16(
              pf[0][c], bv[n][c], o_acc[0][n], 0, 0, 0);
          o_acc[1][n] = __builtin_amdgcn_mfma_f32_16x16x32_bf16(
              pf[1][c], bv[n][c], o_acc[1][n], 0, 0, 0);
        }

      // Stage prefetched K tile into the other buffer.
      if (kt + 1 < ktiles) {
        const int nxt = cur ^ 1;
        *(uint4*)&Ks[nxt][rr * LK + dc] = rk0;
        *(uint4*)&Ks[nxt][rr * LK + dc + 8] = rk1;
      }
      cur ^= 1;
    }

    // Epilogue: l already reduced by MFMA; normalize, store bf16 (in-place q).
#pragma unroll
    for (int r = 0; r < 2; r++)
#pragma unroll
      for (int e = 0; e < 4; e++) {
        const float inv = 1.f / l_acc[r][e];
        const size_t row = (size_t)(b * S_LEN + row0 + wave * 32 + r * 16 +
                                    quad * 4 + e);
#pragma unroll
        for (int n = 0; n < 4; n++)
          ao[row * QKV_LD + h * H_D + n * 16 + l16] =
              f2bf(o_acc[r][n][e] * inv);
      }
  }
}

// ---------------------------------------------------------------------------
// Round-4 attention (fallback path only): k/v separate buffers stride 512.
// ---------------------------------------------------------------------------
__global__ __launch_bounds__(256) void attn_mfma_k(
    const unsigned short* __restrict__ q, const unsigned short* __restrict__ k,
    const unsigned short* __restrict__ v, unsigned short* __restrict__ ao) {
  const int qt = blockIdx.x, h = blockIdx.y, b = blockIdx.z;
  const int hk = h >> 2;
  const int tid = threadIdx.x;
  const int wave = tid >> 6;
  const int l16 = tid & 15;
  const int quad = (tid & 63) >> 4;

  __shared__ __align__(16) unsigned short Ks[64 * LK];
  __shared__ __align__(16) unsigned short Vt[64 * LK];
  __shared__ __align__(16) unsigned short Ps[64 * LK];

  bf16x8 af[2];
  {
    const size_t qrow = (size_t)(b * S_LEN + qt * 64 + wave * 16 + l16);
#pragma unroll
    for (int c = 0; c < 2; c++)
      af[c] = *(const bf16x8*)&q[qrow * DMODEL + h * H_D + c * 32 + quad * 8];
  }

  f32x4 o_acc[4] = {};
  float m_i[4], l_i[4];
#pragma unroll
  for (int e = 0; e < 4; e++) { m_i[e] = -INFINITY; l_i[e] = 0.f; }

  for (int kt = 0; kt <= qt; ++kt) {
    const int kb = kt * 64;
    __syncthreads();
    {
      const int kr = tid >> 2;
      const int dc = (tid & 3) * 16;
      const size_t gro = (size_t)(b * S_LEN + kb + kr) * (N_KV * H_D) + hk * H_D + dc;
      *(uint4*)&Ks[kr * LK + dc] = *(const uint4*)&k[gro];
      *(uint4*)&Ks[kr * LK + dc + 8] = *(const uint4*)&k[gro + 8];
      union { unsigned short u[8]; uint4 v; } w0, w1;
      w0.v = *(const uint4*)&v[gro];
      w1.v = *(const uint4*)&v[gro + 8];
#pragma unroll
      for (int j = 0; j < 8; j++) Vt[(dc + j) * LK + kr] = w0.u[j];
#pragma unroll
      for (int j = 0; j < 8; j++) Vt[(dc + 8 + j) * LK + kr] = w1.u[j];
    }
    __syncthreads();

    f32x4 sacc[4];
#pragma unroll
    for (int n = 0; n < 4; n++) {
      f32x4 z = {};
#pragma unroll
      for (int c = 0; c < 2; c++) {
        const bf16x8 bk = *(const bf16x8*)&Ks[(n * 16 + l16) * LK + c * 32 + quad * 8];
        z = __builtin_amdgcn_mfma_f32_16x16x32_bf16(af[c], bk, z, 0, 0, 0);
      }
      sacc[n] = z;
    }

    float p[4][4], mnew[4];
#pragma unroll
    for (int e = 0; e < 4; e++) mnew[e] = m_i[e];
#pragma unroll
    for (int n = 0; n < 4; n++)
#pragma unroll
      for (int e = 0; e < 4; e++) {
        float s = sacc[n][e] * 0.125f;
        if (kt == qt && (n * 16 + l16) > (wave * 16 + quad * 4 + e))
          s = -INFINITY;
        p[n][e] = s;
        mnew[e] = fmaxf(mnew[e], s);
      }
#pragma unroll
    for (int e = 0; e < 4; e++) {
      mnew[e] = fmaxf(mnew[e], __shfl_xor(mnew[e], 1));
      mnew[e] = fmaxf(mnew[e], __shfl_xor(mnew[e], 2));
      mnew[e] = fmaxf(mnew[e], __shfl_xor(mnew[e], 4));
      mnew[e] = fmaxf(mnew[e], __shfl_xor(mnew[e], 8));
      const float alpha = __expf(m_i[e] - mnew[e]);
      m_i[e] = mnew[e];
      l_i[e] *= alpha;
#pragma unroll
      for (int n = 0; n < 4; n++) o_acc[n][e] *= alpha;
    }
#pragma unroll
    for (int n = 0; n < 4; n++)
#pragma unroll
      for (int e = 0; e < 4; e++) {
        const float pe = __expf(p[n][e] - m_i[e]);
        p[n][e] = pe;
        l_i[e] += pe;
      }

#pragma unroll
    for (int n = 0; n < 4; n++)
#pragma unroll
      for (int e = 0; e < 4; e++)
        Ps[(wave * 16 + quad * 4 + e) * LK + n * 16 + l16] = f2bf(p[n][e]);
    __syncthreads();

    bf16x8 pf[2];
#pragma unroll
    for (int c = 0; c < 2; c++)
      pf[c] = *(const bf16x8*)&Ps[(wave * 16 + l16) * LK + c * 32 + quad * 8];
#pragma unroll
    for (int n = 0; n < 4; n++)
#pragma unroll
      for (int c = 0; c < 2; c++) {
        const bf16x8 bv = *(const bf16x8*)&Vt[(n * 16 + l16) * LK + c * 32 + quad * 8];
        o_acc[n] = __builtin_amdgcn_mfma_f32_16x16x32_bf16(pf[c], bv, o_acc[n], 0, 0, 0);
      }
  }

#pragma unroll
  for (int e = 0; e < 4; e++) {
    l_i[e] += __shfl_xor(l_i[e], 1);
    l_i[e] += __shfl_xor(l_i[e], 2);
    l_i[e] += __shfl_xor(l_i[e], 4);
    l_i[e] += __shfl_xor(l_i[e], 8);
    const float inv = 1.f / l_i[e];
    const size_t row = (size_t)(b * S_LEN + qt * 64 + wave * 16 + quad * 4 + e);
#pragma unroll
    for (int n = 0; n < 4; n++)
      ao[row * DMODEL + h * H_D + n * 16 + l16] = f2bf(o_acc[n][e] * inv);
  }
}

// ---------------------------------------------------------------------------
extern "C" void kernel_launch(void* const* d_in, const int* in_sizes, int n_in,
                              void* d_out, int out_size, void* d_ws, size_t ws_size,
                              hipStream_t stream) {
  const float* x = (const float*)d_in[0];
  const float* fc = (const float*)d_in[1];
  const float* fs = (const float*)d_in[2];
  const float* wq = (const float*)d_in[3];
  const float* wk = (const float*)d_in[4];
  const float* wv = (const float*)d_in[5];
  const float* wo = (const float*)d_in[6];

  char* ws = (char*)d_ws;
  const dim3 b256(256);

  if (ws_size >= (64ull << 20)) {
    // Fast path (64 MB):
    //   qkv   bf16 [4096][3072] @ 0     (24 MB)  q|k|v fused; attn out in q cols
    //   xb    bf16 [4096][2048] @ 24 MB (16 MB)
    //   wqkvT bf16 [3072][2048] @ 40 MB (12 MB)
    //   woT   bf16 [2048][2048] @ 52 MB ( 8 MB)
    //   vT    bf16 [ 512][4096] @ 60 MB ( 4 MB)
    unsigned short* qkv = (unsigned short*)(ws);
    unsigned short* xb = (unsigned short*)(ws + (24ull << 20));
    unsigned short* wqkvT = (unsigned short*)(ws + (40ull << 20));
    unsigned short* woT = (unsigned short*)(ws + (52ull << 20));
    unsigned short* vT = (unsigned short*)(ws + (60ull << 20));

    prep_all_k<<<dim3(64, 64, 5), b256, 0, stream>>>(x, wq, wk, wv, wo, xb,
                                                     wqkvT, woT);

    // One fused QKV projection: [4096][2048] @ [3072][2048]^T -> [4096][3072]
    gemm_bt_k<1><<<dim3(32, 24), b256, 0, stream>>>(xb, wqkvT, qkv, 4096, 3072,
                                                    2048, 2048);

    // RoPE (q pre-scaled by log2e/8, k plain) + v -> vT transpose, fused
    rope_vt_k<<<dim3(20480 + 2048), b256, 0, stream>>>(qkv, vT, fc, fs);

    attn_mfma7_k<<<dim3(8, N_H, 2), b256, 0, stream>>>(qkv, vT, qkv);

    // Output projection reads attn output (qkv q-cols, lda=3072) -> fp32 d_out
    gemm_bt_k<0><<<dim3(32, 16), b256, 0, stream>>>(qkv, woT, d_out, 4096, 2048,
                                                    2048, QKV_LD);
  } else {
    // Round-4 fallback (<= 40 MB)
    unsigned short* q = (unsigned short*)(ws);
    unsigned short* k = (unsigned short*)(ws + (16ull << 20));
    unsigned short* v = (unsigned short*)(ws + (20ull << 20));
    unsigned short* xb = (unsigned short*)(ws + (24ull << 20));
    const bool have_xb = ws_size >= (40ull << 20);

    if (have_xb) {
      cvt_bf16_k<<<dim3(ROWS * DMODEL / (256 * 8)), b256, 0, stream>>>(x, xb);
      gemm_k<0, 1><<<dim3(32, 16), b256, 0, stream>>>(xb, wq, q, 4096, 2048, 2048);
      gemm_k<0, 1><<<dim3(32, 4), b256, 0, stream>>>(xb, wk, k, 4096, 512, 2048);
      gemm_k<0, 1><<<dim3(32, 4), b256, 0, stream>>>(xb, wv, v, 4096, 512, 2048);
    } else {
      gemm_k<1, 1><<<dim3(32, 16), b256, 0, stream>>>(x, wq, q, 4096, 2048, 2048);
      gemm_k<1, 1><<<dim3(32, 4), b256, 0, stream>>>(x, wk, k, 4096, 512, 2048);
      gemm_k<1, 1><<<dim3(32, 4), b256, 0, stream>>>(x, wv, v, 4096, 512, 2048);
    }

    rope_k<<<dim3(20480), b256, 0, stream>>>(q, k, fc, fs, N_H * H_D, N_KV * H_D);
    attn_mfma_k<<<dim3(S_LEN / 64, N_H, 2), b256, 0, stream>>>(q, k, v, q);
    gemm_k<0, 0><<<dim3(32, 16), b256, 0, stream>>>(q, wo, d_out, 4096, 2048, 2048);
  }
}